// Round 3
// baseline (107.979 us; speedup 1.0000x reference)
//
#include <hip/hip_runtime.h>
#include <hip/hip_bf16.h>
#include <cstdint>

#define DEVFN __device__ __forceinline__

namespace {

constexpr int B = 16, T = 8192, C = 128, H = 128, K = 5;
constexpr int TP1 = T + 1;                      // 8193 slots (slot 0 = init row)
constexpr int N = B * TP1 * H;                  // 16,779,264
constexpr int NKK = 20;                         // (C*K)/32 K-steps
constexpr int NCH = T / 64;                     // 128 chunks over slots [1+64j, 64+64j]
constexpr int NSER = B * H;                     // 2048 scan series
constexpr int WF_ELE = NKK * 8 * 64 * 2 * 8;    // bf16 fragment elems (F+Z interleaved)
constexpr int XPITCH = 136;                     // LDS row pitch in shorts (272 B = 17*16B)
constexpr int BM = 128;                         // rows (time steps) per conv block
constexpr int XROWS = BM + 4;                   // 132 staged rows

typedef __attribute__((ext_vector_type(8))) short short8;
typedef __attribute__((ext_vector_type(4))) float f32x4;

DEVFN float sigmoidf(float x) { return 1.0f / (1.0f + __expf(-x)); }
DEVFN unsigned bfb(float v) {
  __hip_bfloat16 h = __float2bfloat16(v);
  return (unsigned)*reinterpret_cast<unsigned short*>(&h);
}

// Segment-summary compose: L=[..b] then R=[b+1..]:
//   P* = P*_L * Fl_L * P*_R ; Q = Fl_L * P*_R * Q_L + Q_R ; Fl = Fl_R
DEVFN void compose(float& P, float& Q, float& Fl, float Pr, float Qr, float Flr) {
  float t = Fl * Pr;
  P = P * t;
  Q = fmaf(t, Q, Qr);
  Fl = Flr;
}

// ---------------------------------------------------------------------------
// Weights (H,C,K) f32 -> MFMA B-fragment layout bf16 (16x16x32), F/Z interleaved:
//   idx = (((kk*8 + nf8)*64 + lane)*2 + fz)*8 + j
//   value = Bmat[kdim = kk*32 + (lane>>4)*8 + j][h = nf8*16 + (lane&15)]
//   fz==0 -> f_w, fz==1 -> z_w.
__global__ __launch_bounds__(256)
void wprep_kernel(const float* __restrict__ fw, const float* __restrict__ zw,
                  short* __restrict__ Wfrag) {
  int idx = blockIdx.x * 256 + threadIdx.x;
  if (idx >= WF_ELE) return;
  int j = idx & 7;
  int fz = (idx >> 3) & 1;
  int lane = (idx >> 4) & 63;
  int nf8 = (idx >> 10) & 7;
  int kk = idx >> 13;
  int kdim = kk * 32 + ((lane >> 4) << 3) + j;
  int h = nf8 * 16 + (lane & 15);
  int k = kdim >> 7, c = kdim & 127;
  int src = (h * C + c) * K + k;
  float w = fz ? zw[src] : fw[src];
  Wfrag[idx] = (short)bfb(w);
}

// ---------------------------------------------------------------------------
// Conv via MFMA + in-epilogue chunk summaries.
// Block: 128 t-rows (TWO scan chunks) x batch b. 8 waves = 2M x 4N.
// Wave (wm, wn): rows [wm*64,+64) x h-cols [wn*32,+32), F and Z -> 16 acc frags.
//  - 4 MFMAs per LDS a-frag read (vs 2 in the 64-row version)
//  - weight L2 stream halved (1024 blocks instead of 2048)
//  - FG row-segment per wave = full 128B line, both 64B halves stored
//    back-to-back (fixes round-2 partial-line write amplification)
__global__ __launch_bounds__(512, 4)
void conv_mfma_kernel(const float* __restrict__ x,
                      const float* __restrict__ fb, const float* __restrict__ zb,
                      const short* __restrict__ Wfrag,
                      unsigned* __restrict__ FG,
                      float* __restrict__ sumP, float* __restrict__ sumQ) {
  __shared__ short xs[XROWS * XPITCH];  // rows r <-> t = t0-2+r; 272B pitch
  const int b = blockIdx.y;
  const int t0 = blockIdx.x * BM;
  const int tid = threadIdx.x;
  const int lane = tid & 63;
  const int wid = tid >> 6;
  const int wm = wid >> 2;           // 0..1: row half
  const int wn = wid & 3;            // 0..3: 32-wide h group
  const int lrow = lane & 15;
  const int lg = lane >> 4;

  // ---- stage x tile as bf16 (132 rows x 128 c), linear padded layout ----
  for (int i = tid; i < XROWS * 16; i += 512) {
    int r = i >> 4, co = (i & 15) << 3;
    int t = t0 - 2 + r;
    f32x4 v0 = {0.f, 0.f, 0.f, 0.f}, v1 = v0;
    if (t >= 0 && t < T) {
      const f32x4* p = reinterpret_cast<const f32x4*>(x + ((size_t)(b * T + t)) * C + co);
      v0 = p[0]; v1 = p[1];
    }
    short8 s;
    s[0] = (short)bfb(v0[0]); s[1] = (short)bfb(v0[1]); s[2] = (short)bfb(v0[2]); s[3] = (short)bfb(v0[3]);
    s[4] = (short)bfb(v1[0]); s[5] = (short)bfb(v1[1]); s[6] = (short)bfb(v1[2]); s[7] = (short)bfb(v1[3]);
    *reinterpret_cast<short8*>(xs + r * XPITCH + co) = s;
  }
  __syncthreads();

  f32x4 accF0[4], accZ0[4], accF1[4], accZ1[4];
#pragma unroll
  for (int mf = 0; mf < 4; ++mf) {
    accF0[mf] = {0.f,0.f,0.f,0.f}; accZ0[mf] = {0.f,0.f,0.f,0.f};
    accF1[mf] = {0.f,0.f,0.f,0.f}; accZ1[mf] = {0.f,0.f,0.f,0.f};
  }

  const char* xsb = reinterpret_cast<const char*>(xs);
  // s8 index: kk*1024 + nf8*128 + lane*2 + fz ; wave wn uses nf8 = 2wn, 2wn+1
  const short8* wb = reinterpret_cast<const short8*>(Wfrag) + (wn * 256 + lane * 2);
  const int abase = (wm * 64 + lrow) * 272 + lg * 16;   // byte offset

  // ---- K-loop: barrier-free, fully unrolled, immediate-offset ds_reads ----
#pragma unroll
  for (int kk = 0; kk < NKK; ++kk) {
    const int k = kk >> 2;                 // compile-time
    const int cq = (kk & 3) << 6;          // byte offset within row, compile-time
    const int o = kk * 1024;
    short8 f0 = wb[o], z0 = wb[o + 1], f1 = wb[o + 128], z1 = wb[o + 129];
    short8 a[4];
#pragma unroll
    for (int mf = 0; mf < 4; ++mf)
      a[mf] = *reinterpret_cast<const short8*>(xsb + (abase + (mf * 16 + k) * 272 + cq));
#pragma unroll
    for (int mf = 0; mf < 4; ++mf) {
      accF0[mf] = __builtin_amdgcn_mfma_f32_16x16x32_bf16(a[mf], f0, accF0[mf], 0, 0, 0);
      accZ0[mf] = __builtin_amdgcn_mfma_f32_16x16x32_bf16(a[mf], z0, accZ0[mf], 0, 0, 0);
      accF1[mf] = __builtin_amdgcn_mfma_f32_16x16x32_bf16(a[mf], f1, accF1[mf], 0, 0, 0);
      accZ1[mf] = __builtin_amdgcn_mfma_f32_16x16x32_bf16(a[mf], z1, accZ1[mf], 0, 0, 0);
    }
  }

  // ---- epilogue: fused FG stores (full 128B lines) + 2 chunk summaries ----
  const int h0 = wn * 32 + lrow, h1 = h0 + 16;
  const float bF0 = fb[h0], bZ0 = zb[h0], bF1 = fb[h1], bZ1 = zb[h1];
  float cP0 = 1.f, cQ0 = 0.f, cFl0 = 1.f;
  float cP1 = 1.f, cQ1 = 0.f, cFl1 = 1.f;
#pragma unroll
  for (int mf = 0; mf < 4; ++mf) {
    float y0 = 0.f, P0 = 1.f, pF0 = 1.f;
    float y1 = 0.f, P1 = 1.f, pF1 = 1.f;
#pragma unroll
    for (int j = 0; j < 4; ++j) {
      int m = mf * 16 + lg * 4 + j;
      int s = t0 + wm * 64 + m + 1;             // gate-slot index
      size_t off = (size_t)(b * TP1 + s) * H;
      float F0 = sigmoidf(accF0[mf][j] + bF0);
      float G0 = sigmoidf(accZ0[mf][j] + bZ0) * (1.0f - F0);
      float F1 = sigmoidf(accF1[mf][j] + bF1);
      float G1 = sigmoidf(accZ1[mf][j] + bZ1) * (1.0f - F1);
      FG[off + h0] = bfb(F0) | (bfb(G0) << 16);
      FG[off + h1] = bfb(F1) | (bfb(G1) << 16);
      if (j == 0) { y0 = G0; y1 = G1; }
      else {
        P0 *= pF0; y0 = fmaf(pF0, y0, G0);
        P1 *= pF1; y1 = fmaf(pF1, y1, G1);
      }
      pF0 = F0; pF1 = F1;
    }
    // compose across lg (4 groups of 4 rows) — 2-level tree, valid on lg==0
    float tP0 = P0, tQ0 = y0, tF0 = pF0;
    float tP1 = P1, tQ1 = y1, tF1 = pF1;
    {
      float q;
      q = __shfl(tP0, lane + 16, 64); float r0 = __shfl(tQ0, lane + 16, 64); float s0 = __shfl(tF0, lane + 16, 64);
      compose(tP0, tQ0, tF0, q, r0, s0);
      q = __shfl(tP1, lane + 16, 64); float r1 = __shfl(tQ1, lane + 16, 64); float s1 = __shfl(tF1, lane + 16, 64);
      compose(tP1, tQ1, tF1, q, r1, s1);
      q = __shfl(tP0, lane + 32, 64); r0 = __shfl(tQ0, lane + 32, 64); s0 = __shfl(tF0, lane + 32, 64);
      compose(tP0, tQ0, tF0, q, r0, s0);
      q = __shfl(tP1, lane + 32, 64); r1 = __shfl(tQ1, lane + 32, 64); s1 = __shfl(tF1, lane + 32, 64);
      compose(tP1, tQ1, tF1, q, r1, s1);
    }
    if (mf == 0) { cP0 = tP0; cQ0 = tQ0; cFl0 = tF0; cP1 = tP1; cQ1 = tQ1; cFl1 = tF1; }
    else { compose(cP0, cQ0, cFl0, tP0, tQ0, tF0); compose(cP1, cQ1, cFl1, tP1, tQ1, tF1); }
  }
  if (lg == 0) {
    int cix = blockIdx.x * 2 + wm;
    int sbase = cix * NSER + b * H;
    sumP[sbase + h0] = cP0; sumQ[sbase + h0] = cQ0;
    sumP[sbase + h1] = cP1; sumQ[sbase + h1] = cQ1;
  }
}

// ---------------------------------------------------------------------------
// scanB: init row (slot 0) + sequential chain over chunk summaries.
// cin[j][ser] = carry INTO chunk j (y[64j]); cin aliases sumP (read-before-write).
__global__ void scanB_kernel(const float* __restrict__ init,
                             const unsigned* __restrict__ FG_r,
                             unsigned* __restrict__ FG_w,
                             const float* __restrict__ sumQ,
                             float* __restrict__ sumP_cin,   // in: P*, out: cin
                             float* __restrict__ out) {
  int g = blockIdx.x * blockDim.x + threadIdx.x;   // 0..NSER-1 = b*128+h
  int b = g >> 7, h = g & (H - 1);
  float rf = init[g];
  float rz = init[NSER + g];
  float F0 = sigmoidf(rf), z = sigmoidf(rz);
  float G0 = z * (1.0f - F0);
  size_t base = (size_t)b * TP1 * H + h;
  FG_w[base] = bfb(F0) | (bfb(G0) << 16);
  out[base] = G0;
  float y = G0;        // y[0]
  float prevFl = F0;   // F[slot 64j] for j=0
  for (int j = 0; j < NCH; ++j) {
    int sidx = j * NSER + g;
    float Ps = sumP_cin[sidx];
    float Q  = sumQ[sidx];
    sumP_cin[sidx] = y;                       // cin for chunk j
    y = fmaf(prevFl * Ps, y, Q);              // y[64(j+1)]
    if (j + 1 < NCH)
      prevFl = __uint_as_float(FG_r[base + (size_t)(64 * (j + 1)) * H] << 16);
  }
}

// ---------------------------------------------------------------------------
// scanC: chunk j covers slots [1+64j, 64+64j]; local rescan with carry-in.
__global__ __launch_bounds__(128)
void scanC_kernel(const unsigned* __restrict__ FG, const float* __restrict__ cin,
                  float* __restrict__ out) {
  const int b = blockIdx.y, j = blockIdx.x, h = threadIdx.x;
  const int s0 = 1 + j * 64;
  float y = cin[j * NSER + b * H + h];
  const size_t base = (size_t)b * TP1 * H + h;
  const unsigned* p = FG + base + (size_t)s0 * H;
  float Fprev = __uint_as_float(p[-H] << 16);     // F[64j]
  float* po = out + base + (size_t)s0 * H;
#pragma unroll 8
  for (int t = 0; t < 64; ++t) {
    unsigned u = *p; p += H;
    float G = __uint_as_float(u & 0xffff0000u);
    y = fmaf(Fprev, y, G);
    Fprev = __uint_as_float(u << 16);
    *po = y; po += H;
  }
}

}  // namespace

// ---------------------------------------------------------------------------
extern "C" void kernel_launch(void* const* d_in, const int* in_sizes, int n_in,
                              void* d_out, int out_size, void* d_ws, size_t ws_size,
                              hipStream_t stream) {
  const float* x    = (const float*)d_in[0];
  const float* init = (const float*)d_in[1];
  const float* zw   = (const float*)d_in[2];
  const float* zb   = (const float*)d_in[3];
  const float* fw   = (const float*)d_in[4];
  const float* fb   = (const float*)d_in[5];
  float* out = (float*)d_out;
  char* ws = (char*)d_ws;

  // ws layout: [0,4N) FG; then sumP (1MB, becomes cin), sumQ (1MB), Wfrag (0.33MB).
  unsigned* FG = (unsigned*)ws;
  float* sumP = (float*)(ws + (size_t)N * 4);
  float* sumQ = sumP + (size_t)NCH * NSER;
  short* Wfrag = (short*)(sumQ + (size_t)NCH * NSER);

  wprep_kernel<<<(WF_ELE + 255) / 256, 256, 0, stream>>>(fw, zw, Wfrag);
  conv_mfma_kernel<<<dim3(NCH / 2, B), 512, 0, stream>>>(x, fb, zb, Wfrag, FG, sumP, sumQ);
  scanB_kernel<<<16, 128, 0, stream>>>(init, FG, FG, sumQ, sumP, out);
  scanC_kernel<<<dim3(NCH, B), 128, 0, stream>>>(FG, sumP, out);
}